// Round 10
// baseline (423.622 us; speedup 1.0000x reference)
//
#include <hip/hip_runtime.h>

// ---------------------------------------------------------------------------
// SpecDetrTransformerEncoderLayer on MI355X (gfx950)
// BS=4 NQ=12500 D=256 HEADS=8 LEVELS=2 POINTS=4 HD=32 D_FF=2048
// ---------------------------------------------------------------------------

#define NQv 12500
#define BSv 4
#define Dv  256
#define DFF 2048

typedef __attribute__((ext_vector_type(8))) __bf16 bf16x8;
typedef __attribute__((ext_vector_type(4))) float f32x4;

__device__ __forceinline__ ushort f32_to_bf16(float f) {
  unsigned u = __float_as_uint(f);
  u += 0x7FFFu + ((u >> 16) & 1u);
  return (ushort)(u >> 16);
}
__device__ __forceinline__ float bf16_to_f32(ushort u) {
  return __uint_as_float(((unsigned)u) << 16);
}

// ---------------- elementwise f32 -> bf16 ----------------------------------
__global__ __launch_bounds__(256) void conv_bf16_kernel(
    const float* __restrict__ in, ushort* __restrict__ out, int n4) {
  int i = blockIdx.x * 256 + threadIdx.x;
  if (i >= n4) return;
  float4 v = reinterpret_cast<const float4*>(in)[i];
  uint2 st;
  st.x = (unsigned)f32_to_bf16(v.x) | ((unsigned)f32_to_bf16(v.y) << 16);
  st.y = (unsigned)f32_to_bf16(v.z) | ((unsigned)f32_to_bf16(v.w) << 16);
  reinterpret_cast<uint2*>(out)[i] = st;
}

// ------- LDS-tiled transpose+convert: in[K][N] f32 -> out[N][K] bf16 -------
__global__ __launch_bounds__(256) void ttrans_kernel(
    const float* __restrict__ in, ushort* __restrict__ out, int K, int N) {
  __shared__ ushort tl[64][65];
  const int n0 = blockIdx.x * 64, k0 = blockIdx.y * 64;
  const int t = threadIdx.x;
#pragma unroll
  for (int i = 0; i < 16; ++i) {
    int idx = t + 256 * i;
    int r = idx >> 6, c = idx & 63;
    tl[r][c] = f32_to_bf16(in[(size_t)(k0 + r) * N + n0 + c]);
  }
  __syncthreads();
#pragma unroll
  for (int i = 0; i < 16; ++i) {
    int idx = t + 256 * i;
    int r = idx >> 6, c = idx & 63;
    out[(size_t)(n0 + r) * K + k0 + c] = tl[c][r];
  }
}

// ------------- concat-transpose of the 3 projection weights ----------------
__global__ __launch_bounds__(256) void build_wcat_kernel(
    const float* __restrict__ w_val, const float* __restrict__ w_off,
    const float* __restrict__ w_attn, const float* __restrict__ b_val,
    const float* __restrict__ b_off, const float* __restrict__ b_attn,
    ushort* __restrict__ wcat, float* __restrict__ bcat) {
  int i = blockIdx.x * 256 + threadIdx.x;
  if (i < 448 * 256) {
    int n = i >> 8, k = i & 255;
    float v = (n < 256) ? w_val[(size_t)k * 256 + n]
              : (n < 384) ? w_off[(size_t)k * 128 + (n - 256)]
                          : w_attn[(size_t)k * 64 + (n - 384)];
    wcat[i] = f32_to_bf16(v);
  }
  if (i < 512)
    bcat[i] = (i < 256) ? b_val[i] : (i < 384) ? b_off[i - 256]
              : (i < 448) ? b_attn[i - 384] : 0.f;
}

// ---------------- 2-phase double-buffered bf16 MFMA GEMM -------------------
#define TBM 128
#define TBN 128
#define TBK 32

template <int RELU, int NMASK>
__global__ __launch_bounds__(256) void gemm128_kernel(
    const ushort* __restrict__ A, const ushort* __restrict__ Bt,
    const float* __restrict__ bias, ushort* __restrict__ C,
    int M, int K, int ldc, int Nreal) {
  __shared__ ushort lds[4][TBM * TBK];

  const int t = threadIdx.x;
  const int wid = t >> 6, lane = t & 63;
  const int wr = wid >> 1, wc = wid & 1;
  const int m0 = blockIdx.y * TBM;
  const int n0 = blockIdx.x * TBN;

  int srowA[2], srowB[2], gsl[2];
#pragma unroll
  for (int i = 0; i < 2; i++) {
    int row = i * 64 + (t >> 2);
    int ar = m0 + row;
    srowA[i] = (ar < M) ? ar : (M - 1);
    srowB[i] = n0 + row;
    gsl[i] = ((t & 3) ^ ((row >> 1) & 3)) * 8;
  }

  f32x4 acc[4][4] = {};
  const int nt = K / TBK;
  int cur = 0;

#pragma unroll
  for (int i = 0; i < 2; i++) {
    const int ldsoff = (i * 256 + wid * 64) * 8;
    __builtin_amdgcn_global_load_lds(
        (const __attribute__((address_space(1))) void*)(A + (size_t)srowA[i] * K + gsl[i]),
        (__attribute__((address_space(3))) void*)(lds[0] + ldsoff), 16, 0, 0);
    __builtin_amdgcn_global_load_lds(
        (const __attribute__((address_space(1))) void*)(Bt + (size_t)srowB[i] * K + gsl[i]),
        (__attribute__((address_space(3))) void*)(lds[1] + ldsoff), 16, 0, 0);
  }
  __syncthreads();

  const int rl = lane & 15, kh = lane >> 4;
  for (int tk = 0; tk < nt; ++tk) {
    if (tk + 1 < nt) {
      const int k0 = (tk + 1) * TBK;
      const int nb = (cur ^ 1) * 2;
#pragma unroll
      for (int i = 0; i < 2; i++) {
        const int ldsoff = (i * 256 + wid * 64) * 8;
        __builtin_amdgcn_global_load_lds(
            (const __attribute__((address_space(1))) void*)(A + (size_t)srowA[i] * K + k0 + gsl[i]),
            (__attribute__((address_space(3))) void*)(lds[nb] + ldsoff), 16, 0, 0);
        __builtin_amdgcn_global_load_lds(
            (const __attribute__((address_space(1))) void*)(Bt + (size_t)srowB[i] * K + k0 + gsl[i]),
            (__attribute__((address_space(3))) void*)(lds[nb + 1] + ldsoff), 16, 0, 0);
      }
    }
    {
      const ushort* As = lds[cur * 2];
      const ushort* Bs = lds[cur * 2 + 1];
      bf16x8 afr[4], bfr[4];
#pragma unroll
      for (int ni = 0; ni < 4; ni++) {
        int rowb = wc * 64 + ni * 16 + rl;
        int p = kh ^ ((rowb >> 1) & 3);
        bfr[ni] = *reinterpret_cast<const bf16x8*>(Bs + rowb * 32 + p * 8);
      }
#pragma unroll
      for (int mi = 0; mi < 4; mi++) {
        int rowa = wr * 64 + mi * 16 + rl;
        int p = kh ^ ((rowa >> 1) & 3);
        afr[mi] = *reinterpret_cast<const bf16x8*>(As + rowa * 32 + p * 8);
      }
#pragma unroll
      for (int mi = 0; mi < 4; mi++)
#pragma unroll
        for (int ni = 0; ni < 4; ni++)
          acc[mi][ni] = __builtin_amdgcn_mfma_f32_16x16x32_bf16(afr[mi], bfr[ni], acc[mi][ni], 0, 0, 0);
    }
    __syncthreads();
    cur ^= 1;
  }

  ushort* ldsC = lds[0];
  const int rgrp = lane >> 4, cl = lane & 15;
#pragma unroll
  for (int pass = 0; pass < 2; ++pass) {
    if (wr == pass) {
#pragma unroll
      for (int mi = 0; mi < 4; mi++) {
#pragma unroll
        for (int ni = 0; ni < 4; ni++) {
          int col = wc * 64 + ni * 16 + cl;
          float bv = bias[n0 + col];
#pragma unroll
          for (int r = 0; r < 4; r++) {
            int rloc = mi * 16 + rgrp * 4 + r;
            float v = acc[mi][ni][r] + bv;
            if (RELU) v = fmaxf(v, 0.f);
            ldsC[rloc * 132 + col] = f32_to_bf16(v);
          }
        }
      }
    }
    __syncthreads();
    {
      int rloc = t >> 2;
      int row = m0 + pass * 64 + rloc;
      if (row < M) {
#pragma unroll
        for (int j = 0; j < 4; j++) {
          int col = (t & 3) * 32 + j * 8;
          if (!NMASK || n0 + col < Nreal) {
            uint4 v = *reinterpret_cast<const uint4*>(ldsC + rloc * 132 + col);
            *reinterpret_cast<uint4*>(C + (size_t)row * ldc + n0 + col) = v;
          }
        }
      }
    }
    __syncthreads();
  }
}

// ---------------- fused FFN1+ReLU+FFN2+residual+LN1 (v10) ------------------
// 64 rows/block, 4 waves, 256 threads, __syncthreads-based (compiler-managed
// waits -> no vmcnt-pollution hazard). LDS-traffic reduction:
//   - GEMM2's w2 operand: global->VGPR direct (b2rA/b2rB double buffer)
//   - GEMM2 phase is BARRIER-FREE (touches only Hs-read + registers)
//   - B1 staged in 8KB BK=32 slices, 2-buffer ring (gemm128's proven swizzle)
// LDS 66 KB -> 2 blocks/CU.
#define LOADB2(pp, tt, dst)                                                    \
  {                                                                            \
    _Pragma("unroll") for (int ni = 0; ni < 4; ni++) {                         \
      int rowb = wv * 64 + ni * 16 + rl;                                       \
      dst[ni] = *reinterpret_cast<const bf16x8*>(                              \
          w2t + (size_t)rowb * 2048 + (pp) * 128 + ((tt) * 4 + kq) * 8);       \
    }                                                                          \
  }

__global__ __launch_bounds__(256, 2) void ffn_ln_fused_kernel(
    const ushort* __restrict__ xb,   // [M][256] bf16 (LN0 output)
    const ushort* __restrict__ w1t,  // [2048][256] bf16
    const float* __restrict__ b1,
    const ushort* __restrict__ w2t,  // [256][2048] bf16
    const float* __restrict__ b2,
    const float* __restrict__ g1, const float* __restrict__ be1,
    float* __restrict__ out,         // [M][256] f32
    int M) {
  __shared__ ushort lds_all[33024];          // 66 KB
  ushort* As = lds_all;                      // [64][256], phys slot = k ^ (row&7)
  ushort* Hs = lds_all + 16384;              // [64][132]
  ushort* stg0 = lds_all + 24832;            // 2 x 4096 us (8 KB each)

  const int t = threadIdx.x;
  const int wv = t >> 6;        // 0..3
  const int lane = t & 63;
  const int rl = lane & 15, kq = lane >> 4;
  const int cl = lane & 15, g4 = lane >> 4;
  const int m0 = blockIdx.x * 64;

  ushort* stgbuf[2] = {stg0, stg0 + 4096};

  // stage (p, j): w1t rows p*128..+127, K-slice j*32..+32 (8 KB)
  auto issueB1 = [&](int p, int j, ushort* dst) {
#pragma unroll
    for (int ii = 0; ii < 2; ++ii) {
      int row = (t >> 2) + 64 * ii;
      int g = (t & 3) ^ ((row >> 1) & 3);
      __builtin_amdgcn_global_load_lds(
          (const __attribute__((address_space(1))) void*)(
              w1t + (size_t)(p * 128 + row) * 256 + j * 32 + g * 8),
          (__attribute__((address_space(3))) void*)(dst + ((size_t)t + 256 * ii) * 8), 16, 0, 0);
    }
  };

  // ---- prologue: As (8 loads/thread) + stage (0,0) ----
#pragma unroll
  for (int ii = 0; ii < 8; ++ii) {
    int row = (t >> 5) + 8 * ii;
    int g = (t & 31) ^ (row & 7);
    int ar = m0 + row; ar = (ar < M) ? ar : (M - 1);
    __builtin_amdgcn_global_load_lds(
        (const __attribute__((address_space(1))) void*)(xb + (size_t)ar * 256 + g * 8),
        (__attribute__((address_space(3))) void*)(As + ((size_t)t + 256 * ii) * 8), 16, 0, 0);
  }
  issueB1(0, 0, stgbuf[0]);
  __syncthreads();

  f32x4 acc1[4][2] = {};
  f32x4 accF[4][4] = {};
  bf16x8 b2rA[4], b2rB[4];
  int cur = 0;

  for (int p = 0; p < 16; ++p) {
    // ---- GEMM1 phase: 8 steps of BK=32 ----
#pragma unroll
    for (int j = 0; j < 8; ++j) {
      int s = p * 8 + j + 1;
      if (s < 128) issueB1(s >> 3, s & 7, stgbuf[cur ^ 1]);

      const ushort* Bs = stgbuf[cur];
      bf16x8 a1f[4], b1f[2];
      const int slotA = j * 4 + kq;
#pragma unroll
      for (int mi = 0; mi < 4; mi++) {
        int rowa = mi * 16 + rl;
        a1f[mi] = *reinterpret_cast<const bf16x8*>(As + rowa * 256 + (slotA ^ (rowa & 7)) * 8);
      }
#pragma unroll
      for (int ni = 0; ni < 2; ni++) {
        int rowb = wv * 32 + ni * 16 + rl;
        b1f[ni] = *reinterpret_cast<const bf16x8*>(Bs + rowb * 32 + (kq ^ ((rowb >> 1) & 3)) * 8);
      }
      if (j == 6) LOADB2(p, 0, b2rA);
      if (j == 7) LOADB2(p, 1, b2rB);

      __builtin_amdgcn_s_setprio(1);
#pragma unroll
      for (int mi = 0; mi < 4; mi++)
#pragma unroll
        for (int ni = 0; ni < 2; ni++)
          acc1[mi][ni] = __builtin_amdgcn_mfma_f32_16x16x32_bf16(a1f[mi], b1f[ni], acc1[mi][ni], 0, 0, 0);
      __builtin_amdgcn_s_setprio(0);

      if (j == 7) {
        // h = relu(acc1 + b1) -> Hs (stride 132), reset acc1
#pragma unroll
        for (int ni = 0; ni < 2; ni++) {
          int col = wv * 32 + ni * 16 + cl;
          float b1v = b1[p * 128 + col];
#pragma unroll
          for (int mi = 0; mi < 4; mi++) {
#pragma unroll
            for (int r = 0; r < 4; r++) {
              int row = mi * 16 + g4 * 4 + r;
              Hs[row * 132 + col] = f32_to_bf16(fmaxf(acc1[mi][ni][r] + b1v, 0.f));
            }
          }
        }
#pragma unroll
        for (int mi = 0; mi < 4; mi++)
#pragma unroll
          for (int ni = 0; ni < 2; ni++)
            acc1[mi][ni] = (f32x4){0.f, 0.f, 0.f, 0.f};
      }
      __syncthreads();
      cur ^= 1;
    }

    // ---- GEMM2 phase: 4 steps, barrier-free (Hs-read + regs only) ----
#pragma unroll
    for (int tt = 0; tt < 4; ++tt) {
      bf16x8 a2f[4];
#pragma unroll
      for (int mi = 0; mi < 4; mi++) {
        int rowa = mi * 16 + rl;
        a2f[mi] = *reinterpret_cast<const bf16x8*>(Hs + rowa * 132 + (tt * 4 + kq) * 8);
      }
      __builtin_amdgcn_s_setprio(1);
      if ((tt & 1) == 0) {
#pragma unroll
        for (int mi = 0; mi < 4; mi++)
#pragma unroll
          for (int ni = 0; ni < 4; ni++)
            accF[mi][ni] = __builtin_amdgcn_mfma_f32_16x16x32_bf16(a2f[mi], b2rA[ni], accF[mi][ni], 0, 0, 0);
      } else {
#pragma unroll
        for (int mi = 0; mi < 4; mi++)
#pragma unroll
          for (int ni = 0; ni < 4; ni++)
            accF[mi][ni] = __builtin_amdgcn_mfma_f32_16x16x32_bf16(a2f[mi], b2rB[ni], accF[mi][ni], 0, 0, 0);
      }
      __builtin_amdgcn_s_setprio(0);
      if (tt == 0) LOADB2(p, 2, b2rA);
      if (tt == 1) LOADB2(p, 3, b2rB);
    }
  }
  __syncthreads();

  // ---- epilogue: z = accF + b2 + x ; LayerNorm ; f32 out ----
  float* ptab = (float*)stg0;           // [64][4][2] = 2 KB
  float* mtab = (float*)(stg0 + 2048);  // [64][2]

  float b2c[4], g1c[4], bec[4];
#pragma unroll
  for (int ni = 0; ni < 4; ni++) {
    int col = wv * 64 + ni * 16 + cl;
    b2c[ni] = b2[col]; g1c[ni] = g1[col]; bec[ni] = be1[col];
  }
#pragma unroll
  for (int mi = 0; mi < 4; mi++) {
#pragma unroll
    for (int ni = 0; ni < 4; ni++) {
      int col = wv * 64 + ni * 16 + cl;
#pragma unroll
      for (int r = 0; r < 4; r++) {
        int row = mi * 16 + g4 * 4 + r;
        ushort xv = As[row * 256 + ((col >> 3) ^ (row & 7)) * 8 + (col & 7)];
        accF[mi][ni][r] += b2c[ni] + bf16_to_f32(xv);
      }
    }
  }
#pragma unroll
  for (int mi = 0; mi < 4; mi++) {
#pragma unroll
    for (int r = 0; r < 4; r++) {
      float s = accF[mi][0][r] + accF[mi][1][r] + accF[mi][2][r] + accF[mi][3][r];
      float sq = accF[mi][0][r] * accF[mi][0][r] + accF[mi][1][r] * accF[mi][1][r] +
                 accF[mi][2][r] * accF[mi][2][r] + accF[mi][3][r] * accF[mi][3][r];
#pragma unroll
      for (int o = 1; o < 16; o <<= 1) {
        s += __shfl_xor(s, o, 64);
        sq += __shfl_xor(sq, o, 64);
      }
      if (cl == 0) {
        int row = mi * 16 + g4 * 4 + r;
        ptab[(row * 4 + wv) * 2 + 0] = s;
        ptab[(row * 4 + wv) * 2 + 1] = sq;
      }
    }
  }
  __syncthreads();
  {
    int row = t >> 2, part = t & 3;
    float s = ptab[(row * 4 + part) * 2 + 0];
    float sq = ptab[(row * 4 + part) * 2 + 1];
    s += __shfl_xor(s, 1, 64);  sq += __shfl_xor(sq, 1, 64);
    s += __shfl_xor(s, 2, 64);  sq += __shfl_xor(sq, 2, 64);
    if (part == 0) {
      float mean = s * (1.f / 256.f);
      float var = sq * (1.f / 256.f) - mean * mean;
      mtab[row * 2 + 0] = mean;
      mtab[row * 2 + 1] = rsqrtf(var + 1e-5f);
    }
  }
  __syncthreads();
#pragma unroll
  for (int mi = 0; mi < 4; mi++) {
#pragma unroll
    for (int r = 0; r < 4; r++) {
      int row = mi * 16 + g4 * 4 + r;
      float2 ms = *reinterpret_cast<const float2*>(mtab + row * 2);
      int grow = m0 + row;
      if (grow < M) {
#pragma unroll
        for (int ni = 0; ni < 4; ni++) {
          int col = wv * 64 + ni * 16 + cl;
          out[(size_t)grow * 256 + col] = (accF[mi][ni][r] - ms.x) * ms.y * g1c[ni] + bec[ni];
        }
      }
    }
  }
}

// ---------------- deformable attention sampling ----------------------------
__global__ __launch_bounds__(256) void deform_attn_kernel(
    const ushort* __restrict__ pcat, const float* __restrict__ refp,
    ushort* __restrict__ out, int total) {
  int tid = blockIdx.x * 256 + threadIdx.x;
  if (tid >= total) return;
  int c0 = (tid & 3) * 8;
  int idx = tid >> 2;
  int h = idx & 7;
  int row = idx >> 3;
  int bl = row / NQv;

  const ushort* prow = pcat + (size_t)row * 448;

  ushort awr[8];
  *reinterpret_cast<uint4*>(awr) = *reinterpret_cast<const uint4*>(prow + 384 + h * 8);
  float lg[8], mx = -1e30f;
#pragma unroll
  for (int i = 0; i < 8; i++) { lg[i] = bf16_to_f32(awr[i]); mx = fmaxf(mx, lg[i]); }
  float ssum = 0.f;
#pragma unroll
  for (int i = 0; i < 8; i++) { lg[i] = __expf(lg[i] - mx); ssum += lg[i]; }
  float inv = 1.f / ssum;

  ushort ofr[16];
  *reinterpret_cast<uint4*>(ofr)     = *reinterpret_cast<const uint4*>(prow + 256 + h * 16);
  *reinterpret_cast<uint4*>(ofr + 8) = *reinterpret_cast<const uint4*>(prow + 256 + h * 16 + 8);
  float4 rp = *reinterpret_cast<const float4*>(refp + (size_t)row * 4);

  float acc8[8] = {};
  const int Ws[2] = {100, 50}, Hs2[2] = {100, 50}, Ss[2] = {0, 10000};
#pragma unroll
  for (int l = 0; l < 2; l++) {
    const int W = Ws[l], H = Hs2[l];
    float fx = (l ? rp.z : rp.x) * (float)W - 0.5f;
    float fy = (l ? rp.w : rp.y) * (float)H - 0.5f;
    const ushort* vbase = pcat + ((size_t)bl * NQv + Ss[l]) * 448 + h * 32 + c0;
#pragma unroll
    for (int p = 0; p < 4; p++) {
      float x = fx + bf16_to_f32(ofr[l * 8 + p * 2 + 0]);
      float y = fy + bf16_to_f32(ofr[l * 8 + p * 2 + 1]);
      float x0f = floorf(x), y0f = floorf(y);
      float wx1 = x - x0f, wy1 = y - y0f;
      float wx0 = 1.f - wx1, wy0 = 1.f - wy1;
      int x0 = (int)x0f, y0 = (int)y0f;
      float aw = lg[l * 4 + p] * inv;

      float cw[4] = {aw * wx0 * wy0, aw * wx1 * wy0, aw * wx0 * wy1, aw * wx1 * wy1};
      int cx[4] = {x0, x0 + 1, x0, x0 + 1};
      int cy[4] = {y0, y0, y0 + 1, y0 + 1};
#pragma unroll
      for (int c = 0; c < 4; c++) {
        int xi = cx[c], yi = cy[c];
        if (xi >= 0 && xi < W && yi >= 0 && yi < H) {
          ushort vr[8];
          *reinterpret_cast<uint4*>(vr) =
              *reinterpret_cast<const uint4*>(vbase + (size_t)(yi * W + xi) * 448);
          float w = cw[c];
#pragma unroll
          for (int j = 0; j < 8; j++) acc8[j] += w * bf16_to_f32(vr[j]);
        }
      }
    }
  }

  ushort st[8];
#pragma unroll
  for (int j = 0; j < 8; j++) st[j] = f32_to_bf16(acc8[j]);
  *reinterpret_cast<uint4*>(out + (size_t)row * 256 + h * 32 + c0) =
      *reinterpret_cast<uint4*>(st);
}

// ---------------- LN0: x = LN(query_f32 + proj_bf16); out bf16 -------------
__global__ __launch_bounds__(256) void ln0_kernel(
    const float* __restrict__ A, const ushort* __restrict__ B,
    const float* __restrict__ gamma, const float* __restrict__ beta,
    ushort* __restrict__ outb, int M) {
  int row = blockIdx.x * 4 + (threadIdx.x >> 6);
  int lane = threadIdx.x & 63;
  if (row >= M) return;
  size_t base = (size_t)row * 256 + lane * 4;
  float4 a = *reinterpret_cast<const float4*>(A + base);
  uint2 braw = *reinterpret_cast<const uint2*>(B + base);
  float x0 = a.x + bf16_to_f32((ushort)(braw.x & 0xffffu));
  float x1 = a.y + bf16_to_f32((ushort)(braw.x >> 16));
  float x2 = a.z + bf16_to_f32((ushort)(braw.y & 0xffffu));
  float x3 = a.w + bf16_to_f32((ushort)(braw.y >> 16));
  float s = x0 + x1 + x2 + x3;
  float sq = x0 * x0 + x1 * x1 + x2 * x2 + x3 * x3;
#pragma unroll
  for (int o = 1; o < 64; o <<= 1) {
    s += __shfl_xor(s, o, 64);
    sq += __shfl_xor(sq, o, 64);
  }
  float mean = s * (1.f / 256.f);
  float var = sq * (1.f / 256.f) - mean * mean;
  float rs = rsqrtf(var + 1e-5f);
  float4 gv = *reinterpret_cast<const float4*>(gamma + lane * 4);
  float4 bv = *reinterpret_cast<const float4*>(beta + lane * 4);
  float o0 = (x0 - mean) * rs * gv.x + bv.x;
  float o1 = (x1 - mean) * rs * gv.y + bv.y;
  float o2 = (x2 - mean) * rs * gv.z + bv.z;
  float o3 = (x3 - mean) * rs * gv.w + bv.w;
  uint2 st;
  st.x = (unsigned)f32_to_bf16(o0) | ((unsigned)f32_to_bf16(o1) << 16);
  st.y = (unsigned)f32_to_bf16(o2) | ((unsigned)f32_to_bf16(o3) << 16);
  *reinterpret_cast<uint2*>(outb + base) = st;
}

// ---------------------------------------------------------------------------
extern "C" void kernel_launch(void* const* d_in, const int* in_sizes, int n_in,
                              void* d_out, int out_size, void* d_ws, size_t ws_size,
                              hipStream_t stream) {
  const float* query  = (const float*)d_in[0];
  const float* refp   = (const float*)d_in[1];
  const float* w_off  = (const float*)d_in[2];
  const float* b_off  = (const float*)d_in[3];
  const float* w_attn = (const float*)d_in[4];
  const float* b_attn = (const float*)d_in[5];
  const float* w_val  = (const float*)d_in[6];
  const float* b_val  = (const float*)d_in[7];
  const float* w_out  = (const float*)d_in[8];
  const float* b_out  = (const float*)d_in[9];
  const float* w1     = (const float*)d_in[10];
  const float* b1     = (const float*)d_in[11];
  const float* w2     = (const float*)d_in[12];
  const float* b2     = (const float*)d_in[13];
  const float* ln0g   = (const float*)d_in[14];
  const float* ln0b   = (const float*)d_in[15];
  const float* ln1g   = (const float*)d_in[16];
  const float* ln1b   = (const float*)d_in[17];
  float* outp = (float*)d_out;

  char* ws = (char*)d_ws;
  size_t woff = 0;
  auto walloc = [&](size_t bytes) { size_t r = woff; woff += (bytes + 255) & ~(size_t)255; return r; };
  ushort* wcat = (ushort*)(ws + walloc((size_t)512 * 256 * 2));
  float*  bcat = (float*)(ws + walloc(512 * 4));
  ushort* wqt  = (ushort*)(ws + walloc((size_t)256 * 256 * 2));
  ushort* w1t  = (ushort*)(ws + walloc((size_t)DFF * 256 * 2));
  ushort* w2t  = (ushort*)(ws + walloc((size_t)256 * DFF * 2));
  char* arena = ws + woff;
  size_t arena_sz = (ws_size > woff) ? (ws_size - woff) : 0;

  int nb = ((size_t)BSv * NQv * 1920 + (1u << 20) <= arena_sz) ? BSv : 1;
  const int R = nb * NQv;
  ushort* qb   = (ushort*)arena;                       // -> proj
  ushort* pcat = (ushort*)(arena + (size_t)R * 512);
  ushort* samp = (ushort*)(arena + (size_t)R * 1408);  // -> xb
  ushort* proj = qb;
  ushort* xb   = samp;

  build_wcat_kernel<<<dim3(448), dim3(256), 0, stream>>>(
      w_val, w_off, w_attn, b_val, b_off, b_attn, wcat, bcat);
  ttrans_kernel<<<dim3(4, 4), dim3(256), 0, stream>>>(w_out, wqt, Dv, Dv);
  ttrans_kernel<<<dim3(DFF / 64, 4), dim3(256), 0, stream>>>(w1, w1t, Dv, DFF);
  ttrans_kernel<<<dim3(4, DFF / 64), dim3(256), 0, stream>>>(w2, w2t, DFF, Dv);

  const int MT = (R + TBM - 1) / TBM;

  for (int c = 0; c < BSv / nb; c++) {
    const int row0 = c * R;
    const float* qrow = query + (size_t)row0 * Dv;

    conv_bf16_kernel<<<dim3((R * 64 + 255) / 256), dim3(256), 0, stream>>>(qrow, qb, R * 64);

    gemm128_kernel<0, 1><<<dim3(4, MT), dim3(256), 0, stream>>>(
        qb, wcat, bcat, pcat, R, Dv, 448, 448);

    deform_attn_kernel<<<dim3((R * 32 + 255) / 256), dim3(256), 0, stream>>>(
        pcat, refp + (size_t)row0 * 4, samp, R * 32);

    gemm128_kernel<0, 0><<<dim3(2, MT), dim3(256), 0, stream>>>(
        samp, wqt, b_out, proj, R, Dv, 256, 256);

    ln0_kernel<<<dim3((R + 3) / 4), dim3(256), 0, stream>>>(qrow, proj, ln0g, ln0b, xb, R);

    ffn_ln_fused_kernel<<<dim3((R + 63) / 64), dim3(256), 0, stream>>>(
        xb, w1t, b1, w2t, b2, ln1g, ln1b, outp + (size_t)row0 * 256, R);
  }
}

// Round 11
// 328.858 us; speedup vs baseline: 1.2882x; 1.2882x over previous
//
#include <hip/hip_runtime.h>

// ---------------------------------------------------------------------------
// SpecDetrTransformerEncoderLayer on MI355X (gfx950)
// BS=4 NQ=12500 D=256 HEADS=8 LEVELS=2 POINTS=4 HD=32 D_FF=2048
// ---------------------------------------------------------------------------

#define NQv 12500
#define BSv 4
#define Dv  256
#define DFF 2048

typedef __attribute__((ext_vector_type(8))) __bf16 bf16x8;
typedef __attribute__((ext_vector_type(4))) float f32x4;

__device__ __forceinline__ ushort f32_to_bf16(float f) {
  unsigned u = __float_as_uint(f);
  u += 0x7FFFu + ((u >> 16) & 1u);
  return (ushort)(u >> 16);
}
__device__ __forceinline__ float bf16_to_f32(ushort u) {
  return __uint_as_float(((unsigned)u) << 16);
}

// ---------------- elementwise f32 -> bf16 ----------------------------------
__global__ __launch_bounds__(256) void conv_bf16_kernel(
    const float* __restrict__ in, ushort* __restrict__ out, int n4) {
  int i = blockIdx.x * 256 + threadIdx.x;
  if (i >= n4) return;
  float4 v = reinterpret_cast<const float4*>(in)[i];
  uint2 st;
  st.x = (unsigned)f32_to_bf16(v.x) | ((unsigned)f32_to_bf16(v.y) << 16);
  st.y = (unsigned)f32_to_bf16(v.z) | ((unsigned)f32_to_bf16(v.w) << 16);
  reinterpret_cast<uint2*>(out)[i] = st;
}

// ------- LDS-tiled transpose+convert: in[K][N] f32 -> out[N][K] bf16 -------
__global__ __launch_bounds__(256) void ttrans_kernel(
    const float* __restrict__ in, ushort* __restrict__ out, int K, int N) {
  __shared__ ushort tl[64][65];
  const int n0 = blockIdx.x * 64, k0 = blockIdx.y * 64;
  const int t = threadIdx.x;
#pragma unroll
  for (int i = 0; i < 16; ++i) {
    int idx = t + 256 * i;
    int r = idx >> 6, c = idx & 63;
    tl[r][c] = f32_to_bf16(in[(size_t)(k0 + r) * N + n0 + c]);
  }
  __syncthreads();
#pragma unroll
  for (int i = 0; i < 16; ++i) {
    int idx = t + 256 * i;
    int r = idx >> 6, c = idx & 63;
    out[(size_t)(n0 + r) * K + k0 + c] = tl[c][r];
  }
}

// ------------- concat-transpose of the 3 projection weights ----------------
__global__ __launch_bounds__(256) void build_wcat_kernel(
    const float* __restrict__ w_val, const float* __restrict__ w_off,
    const float* __restrict__ w_attn, const float* __restrict__ b_val,
    const float* __restrict__ b_off, const float* __restrict__ b_attn,
    ushort* __restrict__ wcat, float* __restrict__ bcat) {
  int i = blockIdx.x * 256 + threadIdx.x;
  if (i < 448 * 256) {
    int n = i >> 8, k = i & 255;
    float v = (n < 256) ? w_val[(size_t)k * 256 + n]
              : (n < 384) ? w_off[(size_t)k * 128 + (n - 256)]
                          : w_attn[(size_t)k * 64 + (n - 384)];
    wcat[i] = f32_to_bf16(v);
  }
  if (i < 512)
    bcat[i] = (i < 256) ? b_val[i] : (i < 384) ? b_off[i - 256]
              : (i < 448) ? b_attn[i - 384] : 0.f;
}

// ---------------- 2-phase double-buffered bf16 MFMA GEMM -------------------
#define TBM 128
#define TBN 128
#define TBK 32

template <int RELU, int NMASK>
__global__ __launch_bounds__(256) void gemm128_kernel(
    const ushort* __restrict__ A, const ushort* __restrict__ Bt,
    const float* __restrict__ bias, ushort* __restrict__ C,
    int M, int K, int ldc, int Nreal) {
  __shared__ ushort lds[4][TBM * TBK];

  const int t = threadIdx.x;
  const int wid = t >> 6, lane = t & 63;
  const int wr = wid >> 1, wc = wid & 1;
  const int m0 = blockIdx.y * TBM;
  const int n0 = blockIdx.x * TBN;

  int srowA[2], srowB[2], gsl[2];
#pragma unroll
  for (int i = 0; i < 2; i++) {
    int row = i * 64 + (t >> 2);
    int ar = m0 + row;
    srowA[i] = (ar < M) ? ar : (M - 1);
    srowB[i] = n0 + row;
    gsl[i] = ((t & 3) ^ ((row >> 1) & 3)) * 8;
  }

  f32x4 acc[4][4] = {};
  const int nt = K / TBK;
  int cur = 0;

#pragma unroll
  for (int i = 0; i < 2; i++) {
    const int ldsoff = (i * 256 + wid * 64) * 8;
    __builtin_amdgcn_global_load_lds(
        (const __attribute__((address_space(1))) void*)(A + (size_t)srowA[i] * K + gsl[i]),
        (__attribute__((address_space(3))) void*)(lds[0] + ldsoff), 16, 0, 0);
    __builtin_amdgcn_global_load_lds(
        (const __attribute__((address_space(1))) void*)(Bt + (size_t)srowB[i] * K + gsl[i]),
        (__attribute__((address_space(3))) void*)(lds[1] + ldsoff), 16, 0, 0);
  }
  __syncthreads();

  const int rl = lane & 15, kh = lane >> 4;
  for (int tk = 0; tk < nt; ++tk) {
    if (tk + 1 < nt) {
      const int k0 = (tk + 1) * TBK;
      const int nb = (cur ^ 1) * 2;
#pragma unroll
      for (int i = 0; i < 2; i++) {
        const int ldsoff = (i * 256 + wid * 64) * 8;
        __builtin_amdgcn_global_load_lds(
            (const __attribute__((address_space(1))) void*)(A + (size_t)srowA[i] * K + k0 + gsl[i]),
            (__attribute__((address_space(3))) void*)(lds[nb] + ldsoff), 16, 0, 0);
        __builtin_amdgcn_global_load_lds(
            (const __attribute__((address_space(1))) void*)(Bt + (size_t)srowB[i] * K + k0 + gsl[i]),
            (__attribute__((address_space(3))) void*)(lds[nb + 1] + ldsoff), 16, 0, 0);
      }
    }
    {
      const ushort* As = lds[cur * 2];
      const ushort* Bs = lds[cur * 2 + 1];
      bf16x8 afr[4], bfr[4];
#pragma unroll
      for (int ni = 0; ni < 4; ni++) {
        int rowb = wc * 64 + ni * 16 + rl;
        int p = kh ^ ((rowb >> 1) & 3);
        bfr[ni] = *reinterpret_cast<const bf16x8*>(Bs + rowb * 32 + p * 8);
      }
#pragma unroll
      for (int mi = 0; mi < 4; mi++) {
        int rowa = wr * 64 + mi * 16 + rl;
        int p = kh ^ ((rowa >> 1) & 3);
        afr[mi] = *reinterpret_cast<const bf16x8*>(As + rowa * 32 + p * 8);
      }
#pragma unroll
      for (int mi = 0; mi < 4; mi++)
#pragma unroll
        for (int ni = 0; ni < 4; ni++)
          acc[mi][ni] = __builtin_amdgcn_mfma_f32_16x16x32_bf16(afr[mi], bfr[ni], acc[mi][ni], 0, 0, 0);
    }
    __syncthreads();
    cur ^= 1;
  }

  ushort* ldsC = lds[0];
  const int rgrp = lane >> 4, cl = lane & 15;
#pragma unroll
  for (int pass = 0; pass < 2; ++pass) {
    if (wr == pass) {
#pragma unroll
      for (int mi = 0; mi < 4; mi++) {
#pragma unroll
        for (int ni = 0; ni < 4; ni++) {
          int col = wc * 64 + ni * 16 + cl;
          float bv = bias[n0 + col];
#pragma unroll
          for (int r = 0; r < 4; r++) {
            int rloc = mi * 16 + rgrp * 4 + r;
            float v = acc[mi][ni][r] + bv;
            if (RELU) v = fmaxf(v, 0.f);
            ldsC[rloc * 132 + col] = f32_to_bf16(v);
          }
        }
      }
    }
    __syncthreads();
    {
      int rloc = t >> 2;
      int row = m0 + pass * 64 + rloc;
      if (row < M) {
#pragma unroll
        for (int j = 0; j < 4; j++) {
          int col = (t & 3) * 32 + j * 8;
          if (!NMASK || n0 + col < Nreal) {
            uint4 v = *reinterpret_cast<const uint4*>(ldsC + rloc * 132 + col);
            *reinterpret_cast<uint4*>(C + (size_t)row * ldc + n0 + col) = v;
          }
        }
      }
    }
    __syncthreads();
  }
}

// ---------------- fused out-proj + bias + residual + LN0 -------------------
// C = samp @ wqt^T + b_out; x = LN(query + C); write xb bf16.
// 64 rows/block, 4 waves (wave = 64x64 out, 4x4 frags -> 16 MFMA : 8 ds_read
// per BK=32 step). As staged once (32KB); wqt staged per-step (2x16KB ring).
__global__ __launch_bounds__(256, 2) void outproj_ln0_kernel(
    const ushort* __restrict__ samp,  // [M][256] bf16
    const ushort* __restrict__ wqt,   // [256][256] bf16 (N-major)
    const float* __restrict__ bias,   // [256]
    const float* __restrict__ query,  // [M][256] f32
    const float* __restrict__ g0, const float* __restrict__ be0,
    ushort* __restrict__ xb,          // [M][256] bf16
    int M) {
  __shared__ ushort lds_all[32768];          // 64 KB
  ushort* As = lds_all;                      // [64][256], phys slot = k ^ (row&7)
  ushort* ring0 = lds_all + 16384;           // 2 x 8192 us (16 KB each)

  const int t = threadIdx.x;
  const int wv = t >> 6;        // 0..3 (N quarters)
  const int lane = t & 63;
  const int rl = lane & 15, kq = lane >> 4;
  const int cl = lane & 15, g4 = lane >> 4;
  const int m0 = blockIdx.x * 64;

  ushort* ring[2] = {ring0, ring0 + 8192};

  // stage wqt K-slice j*32..+32 for all 256 N-rows (16 KB, 4 issues/thread)
  auto issueB = [&](int j, ushort* dst) {
#pragma unroll
    for (int ii = 0; ii < 4; ++ii) {
      int row = (t >> 2) + 64 * ii;
      int g = (t & 3) ^ ((row >> 1) & 3);
      __builtin_amdgcn_global_load_lds(
          (const __attribute__((address_space(1))) void*)(
              wqt + (size_t)row * 256 + j * 32 + g * 8),
          (__attribute__((address_space(3))) void*)(dst + ((size_t)t + 256 * ii) * 8), 16, 0, 0);
    }
  };

  // prologue: As (8 issues/thread) + B slice 0
#pragma unroll
  for (int ii = 0; ii < 8; ++ii) {
    int row = (t >> 5) + 8 * ii;
    int g = (t & 31) ^ (row & 7);
    int ar = m0 + row; ar = (ar < M) ? ar : (M - 1);
    __builtin_amdgcn_global_load_lds(
        (const __attribute__((address_space(1))) void*)(samp + (size_t)ar * 256 + g * 8),
        (__attribute__((address_space(3))) void*)(As + ((size_t)t + 256 * ii) * 8), 16, 0, 0);
  }
  issueB(0, ring[0]);
  __syncthreads();

  f32x4 accF[4][4] = {};
  int cur = 0;

#pragma unroll
  for (int j = 0; j < 8; ++j) {
    if (j + 1 < 8) issueB(j + 1, ring[cur ^ 1]);
    const ushort* Bs = ring[cur];
    bf16x8 afr[4], bfr[4];
    const int slotA = j * 4 + kq;
#pragma unroll
    for (int mi = 0; mi < 4; mi++) {
      int rowa = mi * 16 + rl;
      afr[mi] = *reinterpret_cast<const bf16x8*>(As + rowa * 256 + (slotA ^ (rowa & 7)) * 8);
    }
#pragma unroll
    for (int ni = 0; ni < 4; ni++) {
      int rowb = wv * 64 + ni * 16 + rl;
      bfr[ni] = *reinterpret_cast<const bf16x8*>(Bs + rowb * 32 + (kq ^ ((rowb >> 1) & 3)) * 8);
    }
    __builtin_amdgcn_s_setprio(1);
#pragma unroll
    for (int mi = 0; mi < 4; mi++)
#pragma unroll
      for (int ni = 0; ni < 4; ni++)
        accF[mi][ni] = __builtin_amdgcn_mfma_f32_16x16x32_bf16(afr[mi], bfr[ni], accF[mi][ni], 0, 0, 0);
    __builtin_amdgcn_s_setprio(0);
    __syncthreads();
    cur ^= 1;
  }

  // ---- epilogue: z = accF + bias + query ; LayerNorm ; write xb bf16 ----
  float* ptab = (float*)ring0;           // [64][4][2] = 2 KB
  float* mtab = (float*)(ring0 + 2048);  // [64][2]

  float bc[4], gc[4], bec[4];
#pragma unroll
  for (int ni = 0; ni < 4; ni++) {
    int col = wv * 64 + ni * 16 + cl;
    bc[ni] = bias[col]; gc[ni] = g0[col]; bec[ni] = be0[col];
  }
#pragma unroll
  for (int mi = 0; mi < 4; mi++) {
#pragma unroll
    for (int ni = 0; ni < 4; ni++) {
      int col = wv * 64 + ni * 16 + cl;
#pragma unroll
      for (int r = 0; r < 4; r++) {
        int row = mi * 16 + g4 * 4 + r;
        int qrow = m0 + row; qrow = (qrow < M) ? qrow : (M - 1);
        accF[mi][ni][r] += bc[ni] + query[(size_t)qrow * 256 + col];
      }
    }
  }
#pragma unroll
  for (int mi = 0; mi < 4; mi++) {
#pragma unroll
    for (int r = 0; r < 4; r++) {
      float s = accF[mi][0][r] + accF[mi][1][r] + accF[mi][2][r] + accF[mi][3][r];
      float sq = accF[mi][0][r] * accF[mi][0][r] + accF[mi][1][r] * accF[mi][1][r] +
                 accF[mi][2][r] * accF[mi][2][r] + accF[mi][3][r] * accF[mi][3][r];
#pragma unroll
      for (int o = 1; o < 16; o <<= 1) {
        s += __shfl_xor(s, o, 64);
        sq += __shfl_xor(sq, o, 64);
      }
      if (cl == 0) {
        int row = mi * 16 + g4 * 4 + r;
        ptab[(row * 4 + wv) * 2 + 0] = s;
        ptab[(row * 4 + wv) * 2 + 1] = sq;
      }
    }
  }
  __syncthreads();
  {
    int row = t >> 2, part = t & 3;
    float s = ptab[(row * 4 + part) * 2 + 0];
    float sq = ptab[(row * 4 + part) * 2 + 1];
    s += __shfl_xor(s, 1, 64);  sq += __shfl_xor(sq, 1, 64);
    s += __shfl_xor(s, 2, 64);  sq += __shfl_xor(sq, 2, 64);
    if (part == 0) {
      float mean = s * (1.f / 256.f);
      float var = sq * (1.f / 256.f) - mean * mean;
      mtab[row * 2 + 0] = mean;
      mtab[row * 2 + 1] = rsqrtf(var + 1e-5f);
    }
  }
  __syncthreads();
#pragma unroll
  for (int mi = 0; mi < 4; mi++) {
#pragma unroll
    for (int r = 0; r < 4; r++) {
      int row = mi * 16 + g4 * 4 + r;
      float2 ms = *reinterpret_cast<const float2*>(mtab + row * 2);
      int grow = m0 + row;
      if (grow < M) {
#pragma unroll
        for (int ni = 0; ni < 4; ni++) {
          int col = wv * 64 + ni * 16 + cl;
          xb[(size_t)grow * 256 + col] =
              f32_to_bf16((accF[mi][ni][r] - ms.x) * ms.y * gc[ni] + bec[ni]);
        }
      }
    }
  }
}

// ---------------- fused FFN1+ReLU+FFN2+residual+LN1 (R6 version) -----------
// 128 rows/block, 8 waves. 128 stages of 16 KB (B1: BK=64 panels, B2: BK=32),
// 3 rotating stage buffers, 2-deep prefetch, counted s_waitcnt vmcnt(4),
// raw s_barrier. Hs [128] stride 136.
__global__ __launch_bounds__(512, 1) void ffn_ln_fused_kernel(
    const ushort* __restrict__ xb,   // [M][256] bf16 (LN0 output)
    const ushort* __restrict__ w1t,  // [2048][256] bf16
    const float* __restrict__ b1,
    const ushort* __restrict__ w2t,  // [256][2048] bf16
    const float* __restrict__ b2,
    const float* __restrict__ g1, const float* __restrict__ be1,
    float* __restrict__ out,         // [M][256] f32
    int M) {
  __shared__ ushort lds_all[74752];            // 146 KB
  ushort* As = lds_all;                        // [128][256], phys = slot^(row&7)
  ushort* Hs = lds_all + 32768;                // [128][136]
  ushort* stg0 = lds_all + 50176;              // 3 x 8192 ushorts

  const int t = threadIdx.x;
  const int wv = t >> 6;
  const int wm = wv >> 2;       // 0..1
  const int wn = wv & 3;        // 0..3
  const int lane = t & 63;
  const int rl = lane & 15, kq = lane >> 4;
  const int cl = lane & 15, g4 = lane >> 4;
  const int m0 = blockIdx.x * 128;

  const int b1row = t >> 3, b1slot = t & 7;
  const int b2row = t >> 2, b2slot = t & 3;

  auto stg = [&](int i) { return stg0 + i * 8192; };

  auto issueB1 = [&](int p, int j, ushort* dst) {
#pragma unroll
    for (int ii = 0; ii < 2; ++ii) {
      int row = b1row + 64 * ii;
      int g = b1slot ^ (row & 7);
      __builtin_amdgcn_global_load_lds(
          (const __attribute__((address_space(1))) void*)(
              w1t + (size_t)(p * 128 + row) * 256 + j * 64 + g * 8),
          (__attribute__((address_space(3))) void*)(dst + (t + 512 * ii) * 8), 16, 0, 0);
    }
  };
  auto issueB2 = [&](int p, int tt, ushort* dst) {
#pragma unroll
    for (int ii = 0; ii < 2; ++ii) {
      int row = b2row + 128 * ii;
      int g = b2slot ^ ((row >> 1) & 3);
      __builtin_amdgcn_global_load_lds(
          (const __attribute__((address_space(1))) void*)(
              w2t + (size_t)row * 2048 + p * 128 + tt * 32 + g * 8),
          (__attribute__((address_space(3))) void*)(dst + (t + 512 * ii) * 8), 16, 0, 0);
    }
  };

  // ---- prologue: As (8 loads) + stage0 + stage1 ----
#pragma unroll
  for (int ii = 0; ii < 8; ++ii) {
    int row = (t >> 5) + 16 * ii;
    int g = (t & 31) ^ (row & 7);
    int ar = m0 + row; ar = (ar < M) ? ar : (M - 1);
    __builtin_amdgcn_global_load_lds(
        (const __attribute__((address_space(1))) void*)(xb + (size_t)ar * 256 + g * 8),
        (__attribute__((address_space(3))) void*)(As + (t + 512 * ii) * 8), 16, 0, 0);
  }
  issueB1(0, 0, stg(0));
  issueB1(0, 1, stg(1));
  asm volatile("s_waitcnt vmcnt(2)" ::: "memory");  // As + stage0 done
  __builtin_amdgcn_s_barrier();

  f32x4 acc1[4][2] = {};
  f32x4 accF[4][4] = {};
  int cur = 0;

  for (int p = 0; p < 16; ++p) {
#pragma unroll
    for (int j = 0; j < 8; ++j) {
      int tgt = cur + 2; if (tgt >= 3) tgt -= 3;
      // issue stage i+2
      if (j <= 5) {
        const int j2 = j + 2;
        const int p2 = p + (j2 >> 3);
        if ((j2 & 7) < 4) issueB1(p2, j2 & 3, stg(tgt));
        else issueB2(p2, (j2 & 7) - 4, stg(tgt));
        asm volatile("s_waitcnt vmcnt(4) lgkmcnt(0)" ::: "memory");
      } else if (p < 15) {
        const int j2m = (j + 2) & 7;  // 0 or 1 -> B1 of p+1
        issueB1(p + 1, j2m, stg(tgt));
        asm volatile("s_waitcnt vmcnt(4) lgkmcnt(0)" ::: "memory");
      } else if (j == 6) {
        asm volatile("s_waitcnt vmcnt(2) lgkmcnt(0)" ::: "memory");
      } else {
        asm volatile("s_waitcnt vmcnt(0) lgkmcnt(0)" ::: "memory");
      }
      __builtin_amdgcn_s_barrier();
      __builtin_amdgcn_sched_barrier(0);

      const ushort* Bs = stg(cur);
      if (j < 4) {
        // ---- GEMM1 step: BK=64 ----
        __builtin_amdgcn_s_setprio(1);
#pragma unroll
        for (int kk = 0; kk < 2; ++kk) {
          bf16x8 afr[4], bfr[2];
          const int slotA = j * 8 + kk * 4 + kq;
#pragma unroll
          for (int mi = 0; mi < 4; mi++) {
            int rowa = wm * 64 + mi * 16 + rl;
            afr[mi] = *reinterpret_cast<const bf16x8*>(As + rowa * 256 + (slotA ^ (rowa & 7)) * 8);
          }
          const int slotB = kk * 4 + kq;
#pragma unroll
          for (int ni = 0; ni < 2; ni++) {
            int rowb = wn * 32 + ni * 16 + rl;
            bfr[ni] = *reinterpret_cast<const bf16x8*>(Bs + rowb * 64 + (slotB ^ (rowb & 7)) * 8);
          }
#pragma unroll
          for (int mi = 0; mi < 4; mi++)
#pragma unroll
            for (int ni = 0; ni < 2; ni++)
              acc1[mi][ni] = __builtin_amdgcn_mfma_f32_16x16x32_bf16(afr[mi], bfr[ni], acc1[mi][ni], 0, 0, 0);
        }
        __builtin_amdgcn_s_setprio(0);
        if (j == 3) {
          // h = relu(acc1 + b1) -> Hs (stride 136), reset acc1
#pragma unroll
          for (int ni = 0; ni < 2; ni++) {
            int col = wn * 32 + ni * 16 + cl;
            float b1v = b1[p * 128 + col];
#pragma unroll
            for (int mi = 0; mi < 4; mi++) {
#pragma unroll
              for (int r = 0; r < 4; r++) {
                int row = wm * 64 + mi * 16 + g4 * 4 + r;
                Hs[row * 136 + col] = f32_to_bf16(fmaxf(acc1[mi][ni][r] + b1v, 0.f));
              }
            }
          }
#pragma unroll
          for (int mi = 0; mi < 4; mi++)
#pragma unroll
            for (int ni = 0; ni < 2; ni++)
              acc1[mi][ni] = (f32x4){0.f, 0.f, 0.f, 0.f};
        }
      } else {
        // ---- GEMM2 step: BK=32 over panel ----
        const int tt = j - 4;
        bf16x8 a2f[4], b2f[4];
#pragma unroll
        for (int mi = 0; mi < 4; mi++) {
          int rowa = wm * 64 + mi * 16 + rl;
          a2f[mi] = *reinterpret_cast<const bf16x8*>(Hs + rowa * 136 + (tt * 4 + kq) * 8);
        }
#pragma unroll
        for (int ni = 0; ni < 4; ni++) {
          int rowb = wn * 64 + ni * 16 + rl;
          b2f[ni] = *reinterpret_cast<const bf16x8*>(Bs + rowb * 32 + (kq ^ ((rowb >> 1) & 3)) * 8);
        }
        __builtin_amdgcn_s_setprio(1);
#pragma unroll
        for (int mi = 0; mi < 4; mi++)
#pragma unroll
          for (int ni = 0; ni < 4; ni++)
            accF[mi][ni] = __builtin_amdgcn_mfma_f32_16x16x32_bf16(a2f[mi], b2f[ni], accF[mi][ni], 0, 0, 0);
        __builtin_amdgcn_s_setprio(0);
      }
      cur = cur + 1; if (cur >= 3) cur -= 3;
    }
  }

  // ---- epilogue: z = accF + b2 + x ; LayerNorm ; f32 out ----
  float* ptab = (float*)stg0;           // [128][4][2]
  float* mtab = (float*)(stg0 + 2048);  // [128][2]

  float b2c[4], g1c[4], bec[4];
#pragma unroll
  for (int ni = 0; ni < 4; ni++) {
    int col = wn * 64 + ni * 16 + cl;
    b2c[ni] = b2[col]; g1c[ni] = g1[col]; bec[ni] = be1[col];
  }
#pragma unroll
  for (int mi = 0; mi < 4; mi++) {
#pragma unroll
    for (int ni = 0; ni < 4; ni++) {
      int col = wn * 64 + ni * 16 + cl;
#pragma unroll
      for (int r = 0; r < 4; r++) {
        int row = wm * 64 + mi * 16 + g4 * 4 + r;
        ushort xv = As[row * 256 + ((col >> 3) ^ (row & 7)) * 8 + (col & 7)];
        accF[mi][ni][r] += b2c[ni] + bf16_to_f32(xv);
      }
    }
  }
#pragma unroll
  for (int mi = 0; mi < 4; mi++) {
#pragma unroll
    for (int r = 0; r < 4; r++) {
      float s = accF[mi][0][r] + accF[mi][1][r] + accF[mi][2][r] + accF[mi][3][r];
      float sq = accF[mi][0][r] * accF[mi][0][r] + accF[mi][1][r] * accF[mi][1][r] +
                 accF[mi][2][r] * accF[mi][2][r] + accF[mi][3][r] * accF[mi][3][r];
#pragma unroll
      for (int o = 1; o < 16; o <<= 1) {
        s += __shfl_xor(s, o, 64);
        sq += __shfl_xor(sq, o, 64);
      }
      if (cl == 0) {
        int row = wm * 64 + mi * 16 + g4 * 4 + r;
        ptab[(row * 4 + wn) * 2 + 0] = s;
        ptab[(row * 4 + wn) * 2 + 1] = sq;
      }
    }
  }
  __syncthreads();
  {
    int row = t >> 2, part = t & 3;
    float s = ptab[(row * 4 + part) * 2 + 0];
    float sq = ptab[(row * 4 + part) * 2 + 1];
    s += __shfl_xor(s, 1, 64);  sq += __shfl_xor(sq, 1, 64);
    s += __shfl_xor(s, 2, 64);  sq += __shfl_xor(sq, 2, 64);
    if (part == 0) {
      float mean = s * (1.f / 256.f);
      float var = sq * (1.f / 256.f) - mean * mean;
      mtab[row * 2 + 0] = mean;
      mtab[row * 2 + 1] = rsqrtf(var + 1e-5f);
    }
  }
  __syncthreads();
#pragma unroll
  for (int mi = 0; mi < 4; mi++) {
#pragma unroll
    for (int r = 0; r < 4; r++) {
      int row = wm * 64 + mi * 16 + g4 * 4 + r;
      float2 ms = *reinterpret_cast<const float2*>(mtab + row * 2);
      int grow = m0 + row;
      if (grow < M) {
#pragma unroll
        for (int ni = 0; ni < 4; ni++) {
          int col = wn * 64 + ni * 16 + cl;
          out[(size_t)grow * 256 + col] = (accF[mi][ni][r] - ms.x) * ms.y * g1c[ni] + bec[ni];
        }
      }
    }
  }
}

// ---------------- deformable attention sampling ----------------------------
__global__ __launch_bounds__(256) void deform_attn_kernel(
    const ushort* __restrict__ pcat, const float* __restrict__ refp,
    ushort* __restrict__ out, int total) {
  int tid = blockIdx.x * 256 + threadIdx.x;
  if (tid >= total) return;
  int c0 = (tid & 3) * 8;
  int idx = tid >> 2;
  int h = idx & 7;
  int row = idx >> 3;
  int bl = row / NQv;

  const ushort* prow = pcat + (size_t)row * 448;

  ushort awr[8];
  *reinterpret_cast<uint4*>(awr) = *reinterpret_cast<const uint4*>(prow + 384 + h * 8);
  float lg[8], mx = -1e30f;
#pragma unroll
  for (int i = 0; i < 8; i++) { lg[i] = bf16_to_f32(awr[i]); mx = fmaxf(mx, lg[i]); }
  float ssum = 0.f;
#pragma unroll
  for (int i = 0; i < 8; i++) { lg[i] = __expf(lg[i] - mx); ssum += lg[i]; }
  float inv = 1.f / ssum;

  ushort ofr[16];
  *reinterpret_cast<uint4*>(ofr)     = *reinterpret_cast<const uint4*>(prow + 256 + h * 16);
  *reinterpret_cast<uint4*>(ofr + 8) = *reinterpret_cast<const uint4*>(prow + 256 + h * 16 + 8);
  float4 rp = *reinterpret_cast<const float4*>(refp + (size_t)row * 4);

  float acc8[8] = {};
  const int Ws[2] = {100, 50}, Hs2[2] = {100, 50}, Ss[2] = {0, 10000};
#pragma unroll
  for (int l = 0; l < 2; l++) {
    const int W = Ws[l], H = Hs2[l];
    float fx = (l ? rp.z : rp.x) * (float)W - 0.5f;
    float fy = (l ? rp.w : rp.y) * (float)H - 0.5f;
    const ushort* vbase = pcat + ((size_t)bl * NQv + Ss[l]) * 448 + h * 32 + c0;
#pragma unroll
    for (int p = 0; p < 4; p++) {
      float x = fx + bf16_to_f32(ofr[l * 8 + p * 2 + 0]);
      float y = fy + bf16_to_f32(ofr[l * 8 + p * 2 + 1]);
      float x0f = floorf(x), y0f = floorf(y);
      float wx1 = x - x0f, wy1 = y - y0f;
      float wx0 = 1.f - wx1, wy0 = 1.f - wy1;
      int x0 = (int)x0f, y0 = (int)y0f;
      float aw = lg[l * 4 + p] * inv;

      float cw[4] = {aw * wx0 * wy0, aw * wx1 * wy0, aw * wx0 * wy1, aw * wx1 * wy1};
      int cx[4] = {x0, x0 + 1, x0, x0 + 1};
      int cy[4] = {y0, y0, y0 + 1, y0 + 1};
#pragma unroll
      for (int c = 0; c < 4; c++) {
        int xi = cx[c], yi = cy[c];
        if (xi >= 0 && xi < W && yi >= 0 && yi < H) {
          ushort vr[8];
          *reinterpret_cast<uint4*>(vr) =
              *reinterpret_cast<const uint4*>(vbase + (size_t)(yi * W + xi) * 448);
          float w = cw[c];
#pragma unroll
          for (int j = 0; j < 8; j++) acc8[j] += w * bf16_to_f32(vr[j]);
        }
      }
    }
  }

  ushort st[8];
#pragma unroll
  for (int j = 0; j < 8; j++) st[j] = f32_to_bf16(acc8[j]);
  *reinterpret_cast<uint4*>(out + (size_t)row * 256 + h * 32 + c0) =
      *reinterpret_cast<uint4*>(st);
}

// ---------------------------------------------------------------------------
extern "C" void kernel_launch(void* const* d_in, const int* in_sizes, int n_in,
                              void* d_out, int out_size, void* d_ws, size_t ws_size,
                              hipStream_t stream) {
  const float* query  = (const float*)d_in[0];
  const float* refp   = (const float*)d_in[1];
  const float* w_off  = (const float*)d_in[2];
  const float* b_off  = (const float*)d_in[3];
  const float* w_attn = (const float*)d_in[4];
  const float* b_attn = (const float*)d_in[5];
  const float* w_val  = (const float*)d_in[6];
  const float* b_val  = (const float*)d_in[7];
  const float* w_out  = (const float*)d_in[8];
  const float* b_out  = (const float*)d_in[9];
  const float* w1     = (const float*)d_in[10];
  const float* b1     = (const float*)d_in[11];
  const float* w2     = (const float*)d_in[12];
  const float* b2     = (const float*)d_in[13];
  const float* ln0g   = (const float*)d_in[14];
  const float* ln0b   = (const float*)d_in[15];
  const float* ln1g   = (const float*)d_in[16];
  const float* ln1b   = (const float*)d_in[17];
  float* outp = (float*)d_out;

  char* ws = (char*)d_ws;
  size_t woff = 0;
  auto walloc = [&](size_t bytes) { size_t r = woff; woff += (bytes + 255) & ~(size_t)255; return r; };
  ushort* wcat = (ushort*)(ws + walloc((size_t)512 * 256 * 2));
  float*  bcat = (float*)(ws + walloc(512 * 4));
  ushort* wqt  = (ushort*)(ws + walloc((size_t)256 * 256 * 2));
  ushort* w1t  = (ushort*)(ws + walloc((size_t)DFF * 256 * 2));
  ushort* w2t  = (ushort*)(ws + walloc((size_t)256 * DFF * 2));
  char* arena = ws + woff;
  size_t arena_sz = (ws_size > woff) ? (ws_size - woff) : 0;

  // arena per chunk (R rows): qb/xb R*512 | pcat R*896 | samp R*512
  int nb = ((size_t)BSv * NQv * 1920 + (1u << 20) <= arena_sz) ? BSv : 1;
  const int R = nb * NQv;
  ushort* qb   = (ushort*)arena;                       // -> xb after out-proj
  ushort* pcat = (ushort*)(arena + (size_t)R * 512);
  ushort* samp = (ushort*)(arena + (size_t)R * 1408);
  ushort* xb   = qb;

  build_wcat_kernel<<<dim3(448), dim3(256), 0, stream>>>(
      w_val, w_off, w_attn, b_val, b_off, b_attn, wcat, bcat);
  ttrans_kernel<<<dim3(4, 4), dim3(256), 0, stream>>>(w_out, wqt, Dv, Dv);
  ttrans_kernel<<<dim3(DFF / 64, 4), dim3(256), 0, stream>>>(w1, w1t, Dv, DFF);
  ttrans_kernel<<<dim3(4, DFF / 64), dim3(256), 0, stream>>>(w2, w2t, DFF, Dv);

  const int MT = (R + TBM - 1) / TBM;

  for (int c = 0; c < BSv / nb; c++) {
    const int row0 = c * R;
    const float* qrow = query + (size_t)row0 * Dv;

    conv_bf16_kernel<<<dim3((R * 64 + 255) / 256), dim3(256), 0, stream>>>(qrow, qb, R * 64);

    gemm128_kernel<0, 1><<<dim3(4, MT), dim3(256), 0, stream>>>(
        qb, wcat, bcat, pcat, R, Dv, 448, 448);

    deform_attn_kernel<<<dim3((R * 32 + 255) / 256), dim3(256), 0, stream>>>(
        pcat, refp + (size_t)row0 * 4, samp, R * 32);

    // fused out-proj + residual + LN0 -> xb (bf16), overwrites qb region
    outproj_ln0_kernel<<<dim3((R + 63) / 64), dim3(256), 0, stream>>>(
        samp, wqt, b_out, qrow, ln0g, ln0b, xb, R);

    // fused FFN + LN1 -> final output
    ffn_ln_fused_kernel<<<dim3((R + 127) / 128), dim3(512), 0, stream>>>(
        xb, w1t, b1, w2t, b2, ln1g, ln1b, outp + (size_t)row0 * 256, R);
  }
}